// Round 1
// baseline (2252.884 us; speedup 1.0000x reference)
//
#include <hip/hip_runtime.h>
#include <stdint.h>

// Problem constants
#define VOCAB 50000
#define EMBD  128
#define HID   256
#define G4    1024   // 4*HID
#define BATCH 256
#define TSEQ  512
#define OUTD  64

typedef __attribute__((ext_vector_type(4))) float f32x4;
typedef __attribute__((ext_vector_type(8))) short short8;

__device__ inline unsigned short f2bf(float f) {
  unsigned u = __float_as_uint(f);
  u += 0x7fffu + ((u >> 16) & 1u);     // round-nearest-even
  return (unsigned short)(u >> 16);
}
__device__ inline float bf2f(unsigned short u) {
  return __uint_as_float(((unsigned)u) << 16);
}
__device__ inline short8 pack2(f32x4 a, f32x4 b) {
  short8 r;
  r[0] = (short)f2bf(a[0]); r[1] = (short)f2bf(a[1]);
  r[2] = (short)f2bf(a[2]); r[3] = (short)f2bf(a[3]);
  r[4] = (short)f2bf(b[0]); r[5] = (short)f2bf(b[1]);
  r[6] = (short)f2bf(b[2]); r[7] = (short)f2bf(b[3]);
  return r;
}
__device__ inline void dma16(const void* g, void* l) {
  __builtin_amdgcn_global_load_lds(
      (const __attribute__((address_space(1))) unsigned int*)g,
      (__attribute__((address_space(3))) unsigned int*)l, 16, 0, 0);
}
__device__ inline float sigmoid_(float x) { return 1.0f / (1.0f + __expf(-x)); }
__device__ inline float tanh_(float x) {
  float e = __expf(2.0f * x);
  return (e - 1.0f) / (e + 1.0f);
}

// Gate permutation: permuted index j' = ha*512 + w*64 + nt*16 + n
//   <->  old gate row oj = nt*256 + ha*128 + (w*16 + n)
// (nt = gate type i/f/g/o, ha = h-half, hu = w*16+n = h-unit within half)

// ---------------------------------------------------------------------------
// K1: Wx[v][j'] = bf16( b_ih[oj] + b_hh[oj] + emb[v] . W_ih[oj] )
// grid (3125, 4), block 256 (4 waves). Wave handles 16 vocab rows x 64 gates.
// ---------------------------------------------------------------------------
__global__ __launch_bounds__(256) void wx_k1(
    const float* __restrict__ emb, const float* __restrict__ Wih,
    const float* __restrict__ bih, const float* __restrict__ bhh,
    unsigned short* __restrict__ Wx) {
  const int vb = blockIdx.x * 16;
  const int jq = blockIdx.y;                    // j' quarter
  const int w1 = threadIdx.x >> 6, lane = threadIdx.x & 63;
  const int quad = lane >> 4, n = lane & 15;

  int ojs[4];
  short8 bfr[4][4];
#pragma unroll
  for (int nt = 0; nt < 4; ++nt) {
    const int jp = jq * 256 + w1 * 64 + nt * 16 + n;
    const int hab = jp >> 9, l = jp & 511;
    const int oj = ((l >> 4) & 3) * 256 + hab * 128 + (l >> 6) * 16 + (l & 15);
    ojs[nt] = oj;
#pragma unroll
    for (int kc = 0; kc < 4; ++kc) {
      const f32x4* wp = (const f32x4*)(Wih + (size_t)oj * EMBD + kc * 32 + quad * 8);
      bfr[nt][kc] = pack2(wp[0], wp[1]);
    }
  }
  short8 af[4];
#pragma unroll
  for (int kc = 0; kc < 4; ++kc) {
    const f32x4* ep = (const f32x4*)(emb + (size_t)(vb + n) * EMBD + kc * 32 + quad * 8);
    af[kc] = pack2(ep[0], ep[1]);
  }
  f32x4 acc[4];
#pragma unroll
  for (int nt = 0; nt < 4; ++nt) acc[nt] = (f32x4){0.f, 0.f, 0.f, 0.f};
#pragma unroll
  for (int kc = 0; kc < 4; ++kc)
#pragma unroll
    for (int nt = 0; nt < 4; ++nt)
      acc[nt] = __builtin_amdgcn_mfma_f32_16x16x32_bf16(af[kc], bfr[nt][kc], acc[nt], 0, 0, 0);
#pragma unroll
  for (int nt = 0; nt < 4; ++nt) {
    const int jp = jq * 256 + w1 * 64 + nt * 16 + n;
    const float bias = bih[ojs[nt]] + bhh[ojs[nt]];
#pragma unroll
    for (int rr = 0; rr < 4; ++rr)
      Wx[(size_t)(vb + quad * 4 + rr) * G4 + jp] = f2bf(acc[nt][rr] + bias);
  }
}

// ---------------------------------------------------------------------------
// K2: persistent LSTM recurrence. 32 WGs x 512 threads.
// WG pair (wg, wg^16) shares 16 batch rows; each holds half of W_hh in regs.
// ---------------------------------------------------------------------------
__global__ __launch_bounds__(512, 2) void lstm_k2(
    const int* __restrict__ x, const float* __restrict__ Whh,
    const unsigned short* __restrict__ Wx,
    unsigned long long* __restrict__ hbuf64,   // [32][2][512] 8B words
    int* __restrict__ flags,                   // [32*16]
    float* __restrict__ lastH) {               // [256][256]
  const int wg = blockIdx.x;
  const int pair = wg & 15, ha = wg >> 4;
  const int partner = wg ^ 16;
  const int tid = threadIdx.x;
  const int w = tid >> 6, lane = tid & 63;
  const int quad = lane >> 4, n = lane & 15;
  const int hu = w * 16 + n;

  __shared__ __attribute__((aligned(16))) unsigned short h_lds[16][264];     // +8 pad
  __shared__ __attribute__((aligned(16))) unsigned short wx_lds[2][16][528]; // +16 pad
  __shared__ unsigned short x_lds[16][TSEQ];
  __shared__ int zpos[16];

  if (tid < 16) zpos[tid] = 1 << 30;
  __syncthreads();
  for (int i = tid; i < 16 * TSEQ; i += 512) {
    const int row = i >> 9, tc = i & 511;
    const int tok = x[(size_t)(pair * 16 + row) * TSEQ + tc];
    x_lds[row][tc] = (unsigned short)tok;
    if (tok == 0) atomicMin(&zpos[row], tc);
  }
  for (int i = tid; i < 16 * 264; i += 512) ((unsigned short*)h_lds)[i] = 0;

  // Preload this half's W_hh as MFMA B-fragments: B[k][n] = Whh[oj(n)][k]
  short8 bfr[4][8];
#pragma unroll
  for (int nt = 0; nt < 4; ++nt) {
    const int oj = nt * 256 + ha * 128 + hu;
#pragma unroll
    for (int kc = 0; kc < 8; ++kc) {
      const f32x4* wp = (const f32x4*)(Whh + (size_t)oj * HID + kc * 32 + quad * 8);
      bfr[nt][kc] = pack2(wp[0], wp[1]);
    }
  }

  float cst[4] = {0.f, 0.f, 0.f, 0.f};
  float lastreg[4] = {0.f, 0.f, 0.f, 0.f};
  __syncthreads();   // x_lds / zpos / h_lds ready
  int idx4[4];
#pragma unroll
  for (int rr = 0; rr < 4; ++rr) idx4[rr] = zpos[quad * 4 + rr] - 1;

  // initial Wx prefetch for t=0 into buffer 0 (wave w fetches rows 2w, 2w+1)
  {
#pragma unroll
    for (int rr2 = 0; rr2 < 2; ++rr2) {
      const int row = w * 2 + rr2;
      int tok = (int)x_lds[row][0];
      tok = __builtin_amdgcn_readfirstlane(tok);
      dma16((const void*)(Wx + (size_t)tok * G4 + ha * 512 + lane * 8),
            (void*)&wx_lds[0][row][0]);
    }
  }
  __syncthreads();   // DMA drained (barrier waits vmcnt)

  unsigned long long* obuf = hbuf64 + (size_t)wg * 1024;
  const unsigned long long* pbuf = hbuf64 + (size_t)partner * 1024;

  for (int t = 0; t < TSEQ; ++t) {
    const int buf = t & 1;
    // prefetch next step's Wx rows into the other buffer
    {
      const int tn = (t + 1 < TSEQ) ? (t + 1) : (TSEQ - 1);
#pragma unroll
      for (int rr2 = 0; rr2 < 2; ++rr2) {
        const int row = w * 2 + rr2;
        int tok = (int)x_lds[row][tn];
        tok = __builtin_amdgcn_readfirstlane(tok);
        dma16((const void*)(Wx + (size_t)tok * G4 + ha * 512 + lane * 8),
              (void*)&wx_lds[buf ^ 1][row][0]);
      }
    }
    // init acc from gathered Wx (includes both biases)
    f32x4 acc[4];
#pragma unroll
    for (int nt = 0; nt < 4; ++nt) {
#pragma unroll
      for (int rr = 0; rr < 4; ++rr)
        acc[nt][rr] = bf2f(wx_lds[buf][quad * 4 + rr][w * 64 + nt * 16 + n]);
    }
    // recurrent GEMM: g += h @ Whh_half^T
#pragma unroll
    for (int kc = 0; kc < 8; ++kc) {
      const short8 af = *(const short8*)&h_lds[n][kc * 32 + quad * 8];
#pragma unroll
      for (int nt = 0; nt < 4; ++nt)
        acc[nt] = __builtin_amdgcn_mfma_f32_16x16x32_bf16(af, bfr[nt][kc], acc[nt], 0, 0, 0);
    }
    // pointwise: lane owns h-unit hu for rows quad*4+rr; acc[nt] = i,f,g,o
#pragma unroll
    for (int rr = 0; rr < 4; ++rr) {
      const float gi = acc[0][rr], gf = acc[1][rr], gg = acc[2][rr], go = acc[3][rr];
      const float ci = sigmoid_(gf) * cst[rr] + sigmoid_(gi) * tanh_(gg);
      cst[rr] = ci;
      const float hv = sigmoid_(go) * tanh_(ci);
      if (t == idx4[rr]) lastreg[rr] = hv;
      h_lds[quad * 4 + rr][ha * 128 + hu] = f2bf(hv);
    }
    __syncthreads();  // own half complete in LDS
    // publish own half to partner (agent-scope, L3-coherent; 8B per thread)
    {
      const int row = tid >> 5, c4 = (tid & 31) * 4;
      const unsigned long long v =
          *(const unsigned long long*)&h_lds[row][ha * 128 + c4];
      __hip_atomic_store(obuf + (size_t)buf * 512 + tid, v,
                         __ATOMIC_RELAXED, __HIP_MEMORY_SCOPE_AGENT);
    }
    __syncthreads();  // all publish stores drained (vmcnt before barrier)
    if (tid == 0) {
      __hip_atomic_store(&flags[wg * 16], t + 1, __ATOMIC_RELEASE,
                         __HIP_MEMORY_SCOPE_AGENT);
      while (__hip_atomic_load(&flags[partner * 16], __ATOMIC_ACQUIRE,
                               __HIP_MEMORY_SCOPE_AGENT) < t + 1) {
      }
    }
    __syncthreads();  // partner's half is visible
    {
      const int row = tid >> 5, c4 = (tid & 31) * 4;
      const unsigned long long v =
          __hip_atomic_load(pbuf + (size_t)buf * 512 + tid,
                            __ATOMIC_RELAXED, __HIP_MEMORY_SCOPE_AGENT);
      *(unsigned long long*)&h_lds[row][(1 - ha) * 128 + c4] = v;
    }
    __syncthreads();  // h_lds full for next step; next Wx DMA drained
  }

  // write the gathered last-valid h (f32, pre-bf16-rounding)
#pragma unroll
  for (int rr = 0; rr < 4; ++rr)
    lastH[(size_t)(pair * 16 + quad * 4 + rr) * HID + ha * 128 + hu] = lastreg[rr];
}

// ---------------------------------------------------------------------------
// K3: logits + softmax. One wave per batch row; lane j = output j.
// ---------------------------------------------------------------------------
__global__ __launch_bounds__(64) void head_k3(
    const float* __restrict__ lastH, const float* __restrict__ Wout,
    const float* __restrict__ bout, float* __restrict__ out) {
  const int b = blockIdx.x, j = threadIdx.x;
  const f32x4* hv = (const f32x4*)(lastH + (size_t)b * HID);
  const f32x4* wv = (const f32x4*)(Wout + (size_t)j * HID);
  float acc = bout[j];
#pragma unroll 8
  for (int k = 0; k < HID / 4; ++k) {
    const f32x4 a = hv[k], ww = wv[k];
    acc += a[0] * ww[0] + a[1] * ww[1] + a[2] * ww[2] + a[3] * ww[3];
  }
  float m = acc;
  for (int s = 32; s > 0; s >>= 1) m = fmaxf(m, __shfl_xor(m, s, 64));
  const float e = __expf(acc - m);
  float ssum = e;
  for (int s = 32; s > 0; s >>= 1) ssum += __shfl_xor(ssum, s, 64);
  out[(size_t)b * OUTD + j] = e / ssum;
}

// ---------------------------------------------------------------------------
extern "C" void kernel_launch(void* const* d_in, const int* in_sizes, int n_in,
                              void* d_out, int out_size, void* d_ws, size_t ws_size,
                              hipStream_t stream) {
  const int*   x    = (const int*)d_in[0];
  const float* emb  = (const float*)d_in[1];
  const float* Wih  = (const float*)d_in[2];
  const float* Whh  = (const float*)d_in[3];
  const float* bih  = (const float*)d_in[4];
  const float* bhh  = (const float*)d_in[5];
  const float* Wout = (const float*)d_in[6];
  const float* bout = (const float*)d_in[7];
  float* out = (float*)d_out;

  // workspace carve (needs ~98.2 MiB)
  char* ws = (char*)d_ws;
  unsigned short* Wx = (unsigned short*)ws;                         // 102,400,000 B
  unsigned long long* hbuf64 = (unsigned long long*)(ws + 102400000); // 262,144 B
  int* flags = (int*)(ws + 102400000 + 262144);                     // 2,048 B
  float* lastH = (float*)(ws + 102400000 + 262144 + 2048);          // 262,144 B

  // flags must start < 1 regardless of workspace poison
  hipMemsetAsync(flags, 0, 32 * 16 * sizeof(int), stream);

  hipLaunchKernelGGL(wx_k1, dim3(3125, 4), dim3(256), 0, stream,
                     emb, Wih, bih, bhh, Wx);
  hipLaunchKernelGGL(lstm_k2, dim3(32), dim3(512), 0, stream,
                     x, Whh, Wx, hbuf64, flags, lastH);
  hipLaunchKernelGGL(head_k3, dim3(BATCH), dim3(OUTD), 0, stream,
                     lastH, Wout, bout, out);
}